// Round 5
// baseline (555.455 us; speedup 1.0000x reference)
//
#include <hip/hip_runtime.h>
#include <hip/hip_bf16.h>

#define B_SZ   8192
#define F_CNT  16
#define E_DIM  32
#define V_CNT  100000
#define D_CNT  8
#define H1     1024
#define H2     512
#define IN_DIM 512
#define EPS_BN 1e-5f
#define SNIFF_THRESH 32

typedef __attribute__((ext_vector_type(8))) unsigned short ushort8;
typedef __attribute__((ext_vector_type(8))) short          frag_ab;
typedef __attribute__((ext_vector_type(4))) float          frag_cd;
typedef __attribute__((ext_vector_type(4))) float          float4v;

__device__ inline unsigned short f2b(float f) {
    unsigned int u = __builtin_bit_cast(unsigned int, f);
    unsigned int r = u + 0x7FFFu + ((u >> 16) & 1u);   // RNE
    return (unsigned short)(r >> 16);
}
__device__ inline float b2f(unsigned short b) {
    return __builtin_bit_cast(float, (unsigned int)b << 16);
}

// ---- dtype sniffer: bf16 data here has |x|<=~1 (exp byte <= 0x7F) -> count 0;
// fp32 read as ushort: even words are random mantissa bits -> ~47% have exp>=0x88.
// Round-4 evidence: fired fp32 on W1 (NaN vanished) => inputs ARE fp32.
__global__ void k_sniff(const unsigned short* __restrict__ w, int nwords,
                        int* __restrict__ cnt) {
    int t = threadIdx.x;
    int c = 0;
    for (int i = t; i < nwords; i += 256) {
        unsigned int e = (w[i] >> 7) & 0xFFu;
        if (e >= 0x88u) c++;
    }
    __shared__ int red[256];
    red[t] = c; __syncthreads();
    for (int s = 128; s > 0; s >>= 1) { if (t < s) red[t] += red[t + s]; __syncthreads(); }
    if (t == 0) atomicAdd(cnt, red[0]);
}

__global__ void k_convert(const void* __restrict__ src, unsigned short* __restrict__ dst,
                          long n, const int* __restrict__ cnt) {
    long i = (long)blockIdx.x * 256 + threadIdx.x;
    if (i >= n) return;
    if (*cnt > SNIFF_THRESH) dst[i] = f2b(((const float*)src)[i]);
    else                     dst[i] = ((const unsigned short*)src)[i];
}

__global__ void k_gather(const int* __restrict__ feat_ids,
                         const void* __restrict__ tables,
                         unsigned short* __restrict__ emb,
                         const int* __restrict__ cnt) {
    int tid = blockIdx.x * 256 + threadIdx.x;    // B*64 threads, 8-elem chunks
    int b = tid >> 6;
    int c = tid & 63;
    int f = c >> 2;
    int id = feat_ids[b * F_CNT + f];
    long base = ((long)f * V_CNT + id) * E_DIM + (c & 3) * 8;
    ushort8 o;
    if (*cnt > SNIFF_THRESH) {
        const float* s = (const float*)tables + base;
        float4v v0 = *(const float4v*)s;
        float4v v1 = *(const float4v*)(s + 4);
#pragma unroll
        for (int i = 0; i < 4; i++) { o[i] = f2b(v0[i]); o[i + 4] = f2b(v1[i]); }
    } else {
        o = *(const ushort8*)((const unsigned short*)tables + base);
    }
    *(ushort8*)(emb + (long)b * IN_DIM + c * 8) = o;
}

__global__ __launch_bounds__(256, 2)
void k_gemm(const unsigned short* __restrict__ A,
            const unsigned short* __restrict__ W,
            unsigned short* __restrict__ C,
            int M, int N, int K, long aBatchStride, int d0) {
    const int z  = blockIdx.z;
    const int m0 = blockIdx.x * 128;
    const int n0 = blockIdx.y * 128;
    const unsigned short* Ad = A + (long)z * aBatchStride;
    const unsigned short* Wd = W + (long)(d0 + z) * N * K;

    __shared__ unsigned short As[128][40];
    __shared__ unsigned short Bs[128][40];

    const int t    = threadIdx.x;
    const int wave = t >> 6;
    const int lane = t & 63;
    const int wm   = (wave & 1) << 6;
    const int wn   = (wave >> 1) << 6;
    const int q    = lane >> 4;
    const int lr   = lane & 15;

    const int r0   = t >> 2;
    const int koff = (t & 3) * 8;

    const unsigned short* aP0 = Ad + (long)(m0 + r0)      * K + koff;
    const unsigned short* aP1 = Ad + (long)(m0 + r0 + 64) * K + koff;
    const unsigned short* wP0 = Wd + (long)(n0 + r0)      * K + koff;
    const unsigned short* wP1 = Wd + (long)(n0 + r0 + 64) * K + koff;

    frag_cd acc[4][4];
#pragma unroll
    for (int i = 0; i < 4; i++)
#pragma unroll
        for (int j = 0; j < 4; j++)
            acc[i][j] = (frag_cd){0.f, 0.f, 0.f, 0.f};

    for (int k0 = 0; k0 < K; k0 += 32) {
        ushort8 a0 = *(const ushort8*)aP0;
        ushort8 a1 = *(const ushort8*)aP1;
        ushort8 b0 = *(const ushort8*)wP0;
        ushort8 b1 = *(const ushort8*)wP1;
        aP0 += 32; aP1 += 32; wP0 += 32; wP1 += 32;
        *(ushort8*)&As[r0][koff]      = a0;
        *(ushort8*)&As[r0 + 64][koff] = a1;
        *(ushort8*)&Bs[r0][koff]      = b0;
        *(ushort8*)&Bs[r0 + 64][koff] = b1;
        __syncthreads();

        frag_ab af[4], bf[4];
#pragma unroll
        for (int i = 0; i < 4; i++) {
            af[i] = *(const frag_ab*)&As[wm + i * 16 + lr][q * 8];
            bf[i] = *(const frag_ab*)&Bs[wn + i * 16 + lr][q * 8];
        }
#pragma unroll
        for (int i = 0; i < 4; i++)
#pragma unroll
            for (int j = 0; j < 4; j++)
                acc[i][j] = __builtin_amdgcn_mfma_f32_16x16x32_bf16(af[i], bf[j], acc[i][j], 0, 0, 0);
        __syncthreads();
    }

    unsigned short* Cd = C + (long)z * M * N;
#pragma unroll
    for (int i = 0; i < 4; i++) {
        int row = m0 + wm + i * 16 + q * 4;          // C/D: col=lane&15, row=quad*4+reg
#pragma unroll
        for (int j = 0; j < 4; j++) {
            int col = n0 + wn + j * 16 + lr;
#pragma unroll
            for (int r = 0; r < 4; r++)
                Cd[(long)(row + r) * N + col] = f2b(acc[i][j][r]);
        }
    }
}

__global__ void k_stats(const unsigned short* __restrict__ P, int H,
                        float* __restrict__ gsum, float* __restrict__ gsq, int d0) {
    const int z   = blockIdx.z;
    const int j0  = blockIdx.x * 128;
    const int seg = blockIdx.y;
    const int t = threadIdx.x;
    const int c = t & 15, r = t >> 4;
    const unsigned short* base = P + ((long)z * B_SZ + seg * 1024) * H + j0 + c * 8;
    float s[8], q[8];
#pragma unroll
    for (int i = 0; i < 8; i++) { s[i] = 0.f; q[i] = 0.f; }
    for (int b = r; b < 1024; b += 16) {
        ushort8 v = *(const ushort8*)(base + (long)b * H);
#pragma unroll
        for (int i = 0; i < 8; i++) { float x = b2f(v[i]); s[i] += x; q[i] += x * x; }
    }
    __shared__ float red[16][128];
#pragma unroll
    for (int i = 0; i < 8; i++) red[r][c * 8 + i] = s[i];
    __syncthreads();
    if (t < 128) {
        float a = 0.f;
#pragma unroll
        for (int rr = 0; rr < 16; rr++) a += red[rr][t];
        atomicAdd(&gsum[(d0 + z) * H + j0 + t], a);
    }
    __syncthreads();
#pragma unroll
    for (int i = 0; i < 8; i++) red[r][c * 8 + i] = q[i];
    __syncthreads();
    if (t < 128) {
        float a = 0.f;
#pragma unroll
        for (int rr = 0; rr < 16; rr++) a += red[rr][t];
        atomicAdd(&gsq[(d0 + z) * H + j0 + t], a);
    }
}

// gOff: element offset into g/be (applied per-dtype on device)
__global__ void k_finalize(const float* __restrict__ gsum, const float* __restrict__ gsq,
                           const void* __restrict__ g, const void* __restrict__ be,
                           float* __restrict__ scale, float* __restrict__ shift, int n,
                           int gOff, const int* __restrict__ cnt) {
    int i = blockIdx.x * 256 + threadIdx.x;
    if (i >= n) return;
    float gv, bv;
    if (*cnt > SNIFF_THRESH) {
        gv = ((const float*)g)[gOff + i];
        bv = ((const float*)be)[gOff + i];
    } else {
        gv = b2f(((const unsigned short*)g)[gOff + i]);
        bv = b2f(((const unsigned short*)be)[gOff + i]);
    }
    float mean = gsum[i] * (1.0f / B_SZ);
    float var  = gsq[i] * (1.0f / B_SZ) - mean * mean;
    float sc   = gv * rsqrtf(var + EPS_BN);
    scale[i] = sc;
    shift[i] = bv - mean * sc;
}

__global__ void k_bn_apply(const unsigned short* __restrict__ P,
                           const float* __restrict__ scale, const float* __restrict__ shift,
                           unsigned short* __restrict__ Out, int H, int d0) {
    long tid = (long)blockIdx.x * 256 + threadIdx.x;
    long off = tid * 8;
    int j  = (int)(off % H);
    int dj = ((int)(off / ((long)B_SZ * H)) + d0) * H + j;
    ushort8 v = *(const ushort8*)(P + off);
    float4v sc0 = *(const float4v*)(scale + dj);
    float4v sc1 = *(const float4v*)(scale + dj + 4);
    float4v sh0 = *(const float4v*)(shift + dj);
    float4v sh1 = *(const float4v*)(shift + dj + 4);
    ushort8 o;
#pragma unroll
    for (int i = 0; i < 8; i++) {
        float scv = (i < 4) ? sc0[i] : sc1[i - 4];
        float shv = (i < 4) ? sh0[i] : sh1[i - 4];
        float x = b2f(v[i]) * scv + shv;
        o[i] = f2b(fmaxf(x, 0.f));
    }
    *(ushort8*)(Out + off) = o;
}

// ---- fused BN2+ReLU+W3 dot+sigmoid+select; OUTPUT dtype follows sniff flag ----
__global__ void k_final(const unsigned short* __restrict__ h2c,
                        const int* __restrict__ domain_id,
                        const float* __restrict__ scale2, const float* __restrict__ shift2,
                        const unsigned short* __restrict__ W3, const unsigned short* __restrict__ b3,
                        void* __restrict__ out, int d0, int nc,
                        const int* __restrict__ cnt) {
    int wave = threadIdx.x >> 6, lane = threadIdx.x & 63;
    int b = blockIdx.x * 4 + wave;
    int d = domain_id[b];
    if (d < d0 || d >= d0 + nc) return;          // wave-uniform (whole wave shares b)
    int o = d * H2 + lane * 8;
    ushort8 v = *(const ushort8*)(h2c + ((long)(d - d0) * B_SZ + b) * H2 + lane * 8);
    ushort8 w = *(const ushort8*)(W3 + o);
    float sum = 0.f;
#pragma unroll
    for (int i = 0; i < 8; i++) {
        float x = b2f(v[i]) * scale2[o + i] + shift2[o + i];
        sum += fmaxf(x, 0.f) * b2f(w[i]);
    }
#pragma unroll
    for (int off = 32; off > 0; off >>= 1) sum += __shfl_xor(sum, off, 64);
    if (lane == 0) {
        float res = 1.f / (1.f + expf(-(sum + b2f(b3[d]))));
        if (*cnt > SNIFF_THRESH) ((float*)out)[b] = res;        // fp32 world (proven)
        else                     ((unsigned short*)out)[b] = f2b(res);
    }
}

__global__ void k_zero(float* __restrict__ p, int n) {
    int i = blockIdx.x * 256 + threadIdx.x;
    if (i < n) p[i] = 0.f;
}

__global__ void k_sentinel(float* __restrict__ out, int n) {
    int i = blockIdx.x * 256 + threadIdx.x;
    if (i < n) out[i] = 0.25f;   // diagnostic: ws too small
}

extern "C" void kernel_launch(void* const* d_in, const int* in_sizes, int n_in,
                              void* d_out, int out_size, void* d_ws, size_t ws_size,
                              hipStream_t stream) {
    const int* feat_ids  = (const int*)d_in[0];
    const int* domain_id = (const int*)d_in[1];
    const void* tables = d_in[2];
    const void* W1  = d_in[3];
    // d_in[4] = b1: mathematically dead (BN subtracts batch mean)
    const void* g1  = d_in[5];
    const void* be1 = d_in[6];
    const void* W2  = d_in[7];
    // d_in[8] = b2: dead
    const void* g2  = d_in[9];
    const void* be2 = d_in[10];
    const void* W3  = d_in[11];
    const void* b3  = d_in[12];

    char* ws = (char*)d_ws;
    float* gsum1  = (float*)ws;
    float* gsq1   = gsum1 + 8192;
    float* gsum2  = gsq1 + 8192;
    float* gsq2   = gsum2 + 4096;
    float* scale1 = gsq2 + 4096;
    float* shift1 = scale1 + 8192;
    float* scale2 = shift1 + 8192;
    float* shift2 = scale2 + 4096;       // end: 49152 floats
    int*   cntF   = (int*)(shift2 + 4096);
    unsigned short* W1c = (unsigned short*)(ws + (1L  << 20));
    unsigned short* W2c = (unsigned short*)(ws + (9L  << 20));
    unsigned short* W3c = (unsigned short*)(ws + (17L << 20));
    unsigned short* b3c = W3c + D_CNT * H2;
    unsigned short* emb = (unsigned short*)(ws + (18L << 20));

    const long h1Elems = (long)B_SZ * H1;
    const long h2Elems = (long)B_SZ * H2;
    const long perDom  = (h1Elems + h2Elems) * 2;
    const long baseOff = 26L << 20;
    int NC = 0;
    for (int cand = 8; cand >= 1; cand >>= 1)
        if (baseOff + (long)cand * perDom <= (long)ws_size) { NC = cand; break; }
    if (NC == 0) {
        k_sentinel<<<dim3((out_size + 255) / 256), dim3(256), 0, stream>>>(
            (float*)d_out, out_size);
        return;
    }
    unsigned short* h1c = (unsigned short*)(ws + baseOff);
    unsigned short* h2c = h1c + (long)NC * h1Elems;

    k_zero<<<dim3(193), dim3(256), 0, stream>>>(gsum1, 49184);   // stats + cntF
    k_sniff<<<dim3(1), dim3(256), 0, stream>>>((const unsigned short*)W1, 4096, cntF);
    k_convert<<<dim3(16384), dim3(256), 0, stream>>>(W1, W1c, (long)D_CNT * H1 * IN_DIM, cntF);
    k_convert<<<dim3(16384), dim3(256), 0, stream>>>(W2, W2c, (long)D_CNT * H2 * H1, cntF);
    k_convert<<<dim3(16),    dim3(256), 0, stream>>>(W3, W3c, (long)D_CNT * H2, cntF);
    k_convert<<<dim3(1),     dim3(256), 0, stream>>>(b3, b3c, (long)D_CNT, cntF);
    k_gather<<<dim3(2048), dim3(256), 0, stream>>>(feat_ids, tables, emb, cntF);

    for (int d0 = 0; d0 < D_CNT; d0 += NC) {
        k_gemm<<<dim3(64, 8, NC), dim3(256), 0, stream>>>(
            emb, W1c, h1c, 8192, 1024, 512, 0L, d0);
        k_stats<<<dim3(8, 8, NC), dim3(256), 0, stream>>>(h1c, H1, gsum1, gsq1, d0);
        k_finalize<<<dim3(NC * 4), dim3(256), 0, stream>>>(
            gsum1 + d0 * H1, gsq1 + d0 * H1, g1, be1,
            scale1 + d0 * H1, shift1 + d0 * H1, NC * H1, d0 * H1, cntF);
        k_bn_apply<<<dim3(NC * 4096), dim3(256), 0, stream>>>(
            h1c, scale1, shift1, h1c, H1, d0);
        k_gemm<<<dim3(64, 4, NC), dim3(256), 0, stream>>>(
            h1c, W2c, h2c, 8192, 512, 1024, h1Elems, d0);
        k_stats<<<dim3(4, 8, NC), dim3(256), 0, stream>>>(h2c, H2, gsum2, gsq2, d0);
        k_finalize<<<dim3(NC * 2), dim3(256), 0, stream>>>(
            gsum2 + d0 * H2, gsq2 + d0 * H2, g2, be2,
            scale2 + d0 * H2, shift2 + d0 * H2, NC * H2, d0 * H2, cntF);
        k_final<<<dim3(2048), dim3(256), 0, stream>>>(
            h2c, domain_id, scale2, shift2, W3c, b3c, d_out, d0, NC, cntF);
    }
}

// Round 6
// 500.199 us; speedup vs baseline: 1.1105x; 1.1105x over previous
//
#include <hip/hip_runtime.h>
#include <hip/hip_bf16.h>

#define B_SZ   8192
#define F_CNT  16
#define E_DIM  32
#define V_CNT  100000
#define D_CNT  8
#define H1     1024
#define H2     512
#define IN_DIM 512
#define EPS_BN 1e-5f

typedef __attribute__((ext_vector_type(8))) unsigned short ushort8;
typedef __attribute__((ext_vector_type(8))) short          frag_ab;
typedef __attribute__((ext_vector_type(4))) float          frag_cd;
typedef __attribute__((ext_vector_type(4))) float          float4v;

__device__ inline unsigned short f2b(float f) {
    unsigned int u = __builtin_bit_cast(unsigned int, f);
    unsigned int r = u + 0x7FFFu + ((u >> 16) & 1u);   // RNE
    return (unsigned short)(r >> 16);
}
__device__ inline float b2f(unsigned short b) {
    return __builtin_bit_cast(float, (unsigned int)b << 16);
}

// async global->LDS DMA, 16B per lane; LDS dest = wave-uniform base + lane*16
__device__ inline void ld_lds16(const unsigned short* g, unsigned short* l) {
    __builtin_amdgcn_global_load_lds(
        (const __attribute__((address_space(1))) unsigned int*)g,
        (__attribute__((address_space(3))) unsigned int*)l, 16, 0, 0);
}

// ---- fp32 -> bf16 weight conversion (proven fp32 inputs, round 4) ------------
__global__ void k_convert(const float* __restrict__ src, unsigned short* __restrict__ dst,
                          long n) {
    long i = ((long)blockIdx.x * 256 + threadIdx.x) * 4;
    if (i >= n) return;
    float4v v = *(const float4v*)(src + i);
    dst[i]     = f2b(v[0]);
    dst[i + 1] = f2b(v[1]);
    dst[i + 2] = f2b(v[2]);
    dst[i + 3] = f2b(v[3]);
}

// ---- embedding gather fp32 tables -> bf16 emb[b, f*32+e] ---------------------
__global__ void k_gather(const int* __restrict__ feat_ids,
                         const float* __restrict__ tables,
                         unsigned short* __restrict__ emb) {
    int tid = blockIdx.x * 256 + threadIdx.x;    // B*64 threads, 8-elem chunks
    int b = tid >> 6;
    int c = tid & 63;
    int f = c >> 2;
    int id = feat_ids[b * F_CNT + f];
    const float* s = tables + ((long)f * V_CNT + id) * E_DIM + (c & 3) * 8;
    float4v v0 = *(const float4v*)s;
    float4v v1 = *(const float4v*)(s + 4);
    ushort8 o;
#pragma unroll
    for (int i = 0; i < 4; i++) { o[i] = f2b(v0[i]); o[i + 4] = f2b(v1[i]); }
    *(ushort8*)(emb + (long)b * IN_DIM + c * 8) = o;
}

// ---- BT GEMM + fused BN-stats: C[z,m,n] = sum_k A·W^T ; gsum/gsq += col sums --
// m97-style: global_load_lds staging (unpadded LDS), 2-barrier K-loop.
__global__ __launch_bounds__(256, 2)
void k_gemm(const unsigned short* __restrict__ A,
            const unsigned short* __restrict__ W,
            unsigned short* __restrict__ C,
            float* __restrict__ gsum, float* __restrict__ gsq,
            int M, int N, int K, long aBatchStride, int d0) {
    const int z  = blockIdx.z;
    const int m0 = blockIdx.x * 128;
    const int n0 = blockIdx.y * 128;
    const unsigned short* Ad = A + (long)z * aBatchStride;
    const unsigned short* Wd = W + (long)(d0 + z) * N * K;

    __shared__ unsigned short As[128 * 32];   // unpadded: required by global_load_lds
    __shared__ unsigned short Bs[128 * 32];

    const int t    = threadIdx.x;
    const int wave = t >> 6;
    const int lane = t & 63;
    const int wm   = (wave & 1) << 6;
    const int wn   = (wave >> 1) << 6;
    const int q    = lane >> 4;
    const int lr   = lane & 15;

    // staging: wave stages rows [wave*32, wave*32+32) of A and B tiles, 2 issues each.
    // lane l covers (row = issueBase + l/4, 8-elem chunk = l%4); LDS dest base+l*16.
    const int srow = lane >> 2;
    const int scol = (lane & 3) * 8;
    const unsigned short* aG0 = Ad + (long)(m0 + wave * 32 + srow) * K + scol;
    const unsigned short* aG1 = aG0 + 16 * (long)K;
    const unsigned short* wG0 = Wd + (long)(n0 + wave * 32 + srow) * K + scol;
    const unsigned short* wG1 = wG0 + 16 * (long)K;
    unsigned short* aL0 = &As[(wave * 32) * 32];       // wave-uniform
    unsigned short* aL1 = &As[(wave * 32 + 16) * 32];
    unsigned short* wL0 = &Bs[(wave * 32) * 32];
    unsigned short* wL1 = &Bs[(wave * 32 + 16) * 32];

    frag_cd acc[4][4];
#pragma unroll
    for (int i = 0; i < 4; i++)
#pragma unroll
        for (int j = 0; j < 4; j++)
            acc[i][j] = (frag_cd){0.f, 0.f, 0.f, 0.f};

    for (int k0 = 0; k0 < K; k0 += 32) {
        ld_lds16(aG0 + k0, aL0);
        ld_lds16(aG1 + k0, aL1);
        ld_lds16(wG0 + k0, wL0);
        ld_lds16(wG1 + k0, wL1);
        __syncthreads();                       // drains vmcnt before barrier

        frag_ab af[4], bf[4];
#pragma unroll
        for (int i = 0; i < 4; i++) {
            af[i] = *(const frag_ab*)&As[(wm + i * 16 + lr) * 32 + q * 8];
            bf[i] = *(const frag_ab*)&Bs[(wn + i * 16 + lr) * 32 + q * 8];
        }
#pragma unroll
        for (int i = 0; i < 4; i++)
#pragma unroll
            for (int j = 0; j < 4; j++)
                acc[i][j] = __builtin_amdgcn_mfma_f32_16x16x32_bf16(af[i], bf[j], acc[i][j], 0, 0, 0);
        __syncthreads();                       // LDS reads done before next DMA
    }

    // ---- epilogue: bf16 C store + fused per-column sum/sumsq (fp32, pre-round)
    unsigned short* Cd = C + (long)z * M * N;
    float s[4], q2[4];
#pragma unroll
    for (int j = 0; j < 4; j++) { s[j] = 0.f; q2[j] = 0.f; }
#pragma unroll
    for (int i = 0; i < 4; i++) {
        int row = m0 + wm + i * 16 + q * 4;          // C/D: col=lane&15, row=quad*4+reg
#pragma unroll
        for (int j = 0; j < 4; j++) {
            int col = n0 + wn + j * 16 + lr;
#pragma unroll
            for (int r = 0; r < 4; r++) {
                float v = acc[i][j][r];
                Cd[(long)(row + r) * N + col] = f2b(v);
                s[j] += v; q2[j] += v * v;
            }
        }
    }
    // collapse the 4 q-quads (same col, different rows): lanes differ in bits 4,5
#pragma unroll
    for (int j = 0; j < 4; j++) {
        s[j]  += __shfl_xor(s[j], 16, 64);  s[j]  += __shfl_xor(s[j], 32, 64);
        q2[j] += __shfl_xor(q2[j], 16, 64); q2[j] += __shfl_xor(q2[j], 32, 64);
    }
    if (lane < 16) {
        float* gs = gsum + (long)(d0 + z) * N + n0 + wn;
        float* gq = gsq  + (long)(d0 + z) * N + n0 + wn;
#pragma unroll
        for (int j = 0; j < 4; j++) {
            atomicAdd(&gs[j * 16 + lane], s[j]);
            atomicAdd(&gq[j * 16 + lane], q2[j]);
        }
    }
}

// ---- stats -> scale/shift (fp32 g/be) ----------------------------------------
__global__ void k_finalize(const float* __restrict__ gsum, const float* __restrict__ gsq,
                           const float* __restrict__ g, const float* __restrict__ be,
                           float* __restrict__ scale, float* __restrict__ shift, int n,
                           int gOff) {
    int i = blockIdx.x * 256 + threadIdx.x;
    if (i >= n) return;
    float mean = gsum[i] * (1.0f / B_SZ);
    float var  = gsq[i] * (1.0f / B_SZ) - mean * mean;
    float sc   = g[gOff + i] * rsqrtf(var + EPS_BN);
    scale[i] = sc;
    shift[i] = be[gOff + i] - mean * sc;
}

// ---- BN apply + ReLU (bf16, in-place) ----------------------------------------
__global__ void k_bn_apply(const unsigned short* __restrict__ P,
                           const float* __restrict__ scale, const float* __restrict__ shift,
                           unsigned short* __restrict__ Out, int H, int d0) {
    long tid = (long)blockIdx.x * 256 + threadIdx.x;
    long off = tid * 8;
    int j  = (int)(off % H);
    int dj = ((int)(off / ((long)B_SZ * H)) + d0) * H + j;
    ushort8 v = *(const ushort8*)(P + off);
    float4v sc0 = *(const float4v*)(scale + dj);
    float4v sc1 = *(const float4v*)(scale + dj + 4);
    float4v sh0 = *(const float4v*)(shift + dj);
    float4v sh1 = *(const float4v*)(shift + dj + 4);
    ushort8 o;
#pragma unroll
    for (int i = 0; i < 8; i++) {
        float scv = (i < 4) ? sc0[i] : sc1[i - 4];
        float shv = (i < 4) ? sh0[i] : sh1[i - 4];
        float x = b2f(v[i]) * scv + shv;
        o[i] = f2b(fmaxf(x, 0.f));
    }
    *(ushort8*)(Out + off) = o;
}

// ---- fused BN2+ReLU+W3 dot+sigmoid+domain select (fp32 out) -------------------
__global__ void k_final(const unsigned short* __restrict__ h2c,
                        const int* __restrict__ domain_id,
                        const float* __restrict__ scale2, const float* __restrict__ shift2,
                        const unsigned short* __restrict__ W3, const unsigned short* __restrict__ b3,
                        float* __restrict__ out, int d0, int nc) {
    int wave = threadIdx.x >> 6, lane = threadIdx.x & 63;
    int b = blockIdx.x * 4 + wave;
    int d = domain_id[b];
    if (d < d0 || d >= d0 + nc) return;          // wave-uniform exit
    int o = d * H2 + lane * 8;
    ushort8 v = *(const ushort8*)(h2c + ((long)(d - d0) * B_SZ + b) * H2 + lane * 8);
    ushort8 w = *(const ushort8*)(W3 + o);
    float sum = 0.f;
#pragma unroll
    for (int i = 0; i < 8; i++) {
        float x = b2f(v[i]) * scale2[o + i] + shift2[o + i];
        sum += fmaxf(x, 0.f) * b2f(w[i]);
    }
#pragma unroll
    for (int off = 32; off > 0; off >>= 1) sum += __shfl_xor(sum, off, 64);
    if (lane == 0)
        out[b] = 1.f / (1.f + expf(-(sum + b2f(b3[d]))));
}

__global__ void k_zero(float* __restrict__ p, int n) {
    int i = blockIdx.x * 256 + threadIdx.x;
    if (i < n) p[i] = 0.f;
}

__global__ void k_sentinel(float* __restrict__ out, int n) {
    int i = blockIdx.x * 256 + threadIdx.x;
    if (i < n) out[i] = 0.25f;   // diagnostic: ws too small
}

extern "C" void kernel_launch(void* const* d_in, const int* in_sizes, int n_in,
                              void* d_out, int out_size, void* d_ws, size_t ws_size,
                              hipStream_t stream) {
    const int*   feat_ids  = (const int*)d_in[0];
    const int*   domain_id = (const int*)d_in[1];
    const float* tables = (const float*)d_in[2];
    const float* W1  = (const float*)d_in[3];
    // d_in[4] = b1: dead (BN subtracts batch mean)
    const float* g1  = (const float*)d_in[5];
    const float* be1 = (const float*)d_in[6];
    const float* W2  = (const float*)d_in[7];
    // d_in[8] = b2: dead
    const float* g2  = (const float*)d_in[9];
    const float* be2 = (const float*)d_in[10];
    const float* W3  = (const float*)d_in[11];
    const float* b3  = (const float*)d_in[12];

    char* ws = (char*)d_ws;
    float* gsum1  = (float*)ws;          // 8192
    float* gsq1   = gsum1 + 8192;        // 8192
    float* gsum2  = gsq1 + 8192;         // 4096
    float* gsq2   = gsum2 + 4096;        // 4096
    float* scale1 = gsq2 + 4096;         // 8192
    float* shift1 = scale1 + 8192;       // 8192
    float* scale2 = shift1 + 8192;       // 4096
    float* shift2 = scale2 + 4096;       // 4096
    unsigned short* W1c = (unsigned short*)(ws + (1L  << 20));
    unsigned short* W2c = (unsigned short*)(ws + (9L  << 20));
    unsigned short* W3c = (unsigned short*)(ws + (17L << 20));
    unsigned short* b3c = W3c + D_CNT * H2;
    unsigned short* emb = (unsigned short*)(ws + (18L << 20));

    const long h1Elems = (long)B_SZ * H1;
    const long h2Elems = (long)B_SZ * H2;
    const long perDom  = (h1Elems + h2Elems) * 2;
    const long baseOff = 26L << 20;
    int NC = 0;
    for (int cand = 8; cand >= 1; cand >>= 1)
        if (baseOff + (long)cand * perDom <= (long)ws_size) { NC = cand; break; }
    if (NC == 0) {
        k_sentinel<<<dim3((out_size + 255) / 256), dim3(256), 0, stream>>>(
            (float*)d_out, out_size);
        return;
    }
    unsigned short* h1c = (unsigned short*)(ws + baseOff);
    unsigned short* h2c = h1c + (long)NC * h1Elems;

    k_zero<<<dim3(96), dim3(256), 0, stream>>>(gsum1, 24576);     // gsum/gsq 1+2
    k_convert<<<dim3(4096), dim3(256), 0, stream>>>(W1, W1c, (long)D_CNT * H1 * IN_DIM);
    k_convert<<<dim3(4096), dim3(256), 0, stream>>>(W2, W2c, (long)D_CNT * H2 * H1);
    k_convert<<<dim3(4),    dim3(256), 0, stream>>>(W3, W3c, (long)D_CNT * H2);
    k_convert<<<dim3(1),    dim3(2),   0, stream>>>(b3, b3c, (long)D_CNT);
    k_gather<<<dim3(2048), dim3(256), 0, stream>>>(feat_ids, tables, emb);

    for (int d0 = 0; d0 < D_CNT; d0 += NC) {
        // Layer 1: M=8192,N=1024,K=512 ; A=emb shared (stride 0); stats fused
        k_gemm<<<dim3(64, 8, NC), dim3(256), 0, stream>>>(
            emb, W1c, h1c, gsum1, gsq1, 8192, 1024, 512, 0L, d0);
        k_finalize<<<dim3(NC * 4), dim3(256), 0, stream>>>(
            gsum1 + d0 * H1, gsq1 + d0 * H1, g1, be1,
            scale1 + d0 * H1, shift1 + d0 * H1, NC * H1, d0 * H1);
        k_bn_apply<<<dim3(NC * 4096), dim3(256), 0, stream>>>(
            h1c, scale1, shift1, h1c, H1, d0);   // in-place
        // Layer 2: M=8192,N=512,K=1024 ; A=h1c batched; stats fused
        k_gemm<<<dim3(64, 4, NC), dim3(256), 0, stream>>>(
            h1c, W2c, h2c, gsum2, gsq2, 8192, 512, 1024, h1Elems, d0);
        k_finalize<<<dim3(NC * 2), dim3(256), 0, stream>>>(
            gsum2 + d0 * H2, gsq2 + d0 * H2, g2, be2,
            scale2 + d0 * H2, shift2 + d0 * H2, NC * H2, d0 * H2);
        k_final<<<dim3(2048), dim3(256), 0, stream>>>(
            h2c, domain_id, scale2, shift2, W3c, b3c, (float*)d_out, d0, NC);
    }
}